// Round 2
// baseline (221.140 us; speedup 1.0000x reference)
//
#include <hip/hip_runtime.h>

// Problem constants (fixed by the reference).
#define T_LEN 4096
#define B_SZ  2
#define H_SZ  2048
#define NM    8            // N2 complex modes
#define BH    (B_SZ * H_SZ)
#define C_CH  64           // number of chunks
#define LC    64           // chunk length (C_CH * LC == T_LEN)
#define H2    (H_SZ / 2)   // h-pairs per batch

// ---------------------------------------------------------------------------
// S4D via chunked linear recurrence (exact equivalent of the FFT conv):
//   S_n(t) = w_n * S_n(t-1) + x(t),  w_n = exp(dt*A_n)
//   out(t) = 2*Re( sum_n Cd_n * S_n(t) ) + D*x(t),  Cd = C*(w-1)/A
// k1: per-(chunk,b,h-pair) local scan -> end states into d_ws
// k2: per-(b,h,n) sequential scan across chunks -> carry-in per chunk
// k3: per-(chunk,b,h-pair) re-scan from carry-in -> output
// All t/c loops are compile-time, software-pipelined in batches of 8 loads
// to keep ~4 KB per wave in flight (latency fix for round-1's 10% HBM BW).
// ---------------------------------------------------------------------------

__device__ __forceinline__ void load_w2(const float* __restrict__ log_dt,
                                        const float* __restrict__ Arl,
                                        const float* __restrict__ Aimp,
                                        int h0,                       // first h of the pair
                                        float wr[2][NM], float wi[2][NM],
                                        float Are[2][NM], float Aim[2][NM]) {
#pragma unroll
    for (int j = 0; j < 2; ++j) {
        int h = h0 + j;
        float dt = __expf(log_dt[h]);
#pragma unroll
        for (int n = 0; n < NM; ++n) {
            float ar = -__expf(Arl[h * NM + n]);
            float ai = Aimp[h * NM + n];
            float er  = __expf(ar * dt);
            float ang = ai * dt;
            wr[j][n] = er * __cosf(ang);
            wi[j][n] = er * __sinf(ang);
            Are[j][n] = ar;
            Aim[j][n] = ai;
        }
    }
}

__global__ void __launch_bounds__(256, 4)
k1_chunk_end(const float* __restrict__ x,
             const float* __restrict__ log_dt,
             const float* __restrict__ Arl,
             const float* __restrict__ Aimp,
             float2* __restrict__ states) {
    int g = blockIdx.x * blockDim.x + threadIdx.x;   // [C_CH * B_SZ * H2)
    int hp = g % H2;
    int b  = (g / H2) % B_SZ;
    int c  = g / (H2 * B_SZ);
    int h0 = hp * 2;

    float wr[2][NM], wi[2][NM], Are[2][NM], Aim[2][NM];
    load_w2(log_dt, Arl, Aimp, h0, wr, wi, Are, Aim);

    float sr[2][NM], si[2][NM];
#pragma unroll
    for (int j = 0; j < 2; ++j)
#pragma unroll
        for (int n = 0; n < NM; ++n) { sr[j][n] = 0.f; si[j][n] = 0.f; }

    const float* xp = x + (size_t)(c * LC) * BH + b * H_SZ + h0;

    float2 buf[8], nxt[8];
#pragma unroll
    for (int i = 0; i < 8; ++i)
        buf[i] = *(const float2*)(xp + (size_t)i * BH);

#pragma unroll
    for (int tb = 0; tb < LC / 8; ++tb) {
        if (tb + 1 < LC / 8) {
#pragma unroll
            for (int i = 0; i < 8; ++i)
                nxt[i] = *(const float2*)(xp + (size_t)((tb + 1) * 8 + i) * BH);
        }
#pragma unroll
        for (int i = 0; i < 8; ++i) {
            float xv[2] = {buf[i].x, buf[i].y};
#pragma unroll
            for (int j = 0; j < 2; ++j) {
#pragma unroll
                for (int n = 0; n < NM; ++n) {
                    float nsr = fmaf(wr[j][n], sr[j][n], fmaf(-wi[j][n], si[j][n], xv[j]));
                    float nsi = fmaf(wr[j][n], si[j][n], wi[j][n] * sr[j][n]);
                    sr[j][n] = nsr; si[j][n] = nsi;
                }
            }
        }
#pragma unroll
        for (int i = 0; i < 8; ++i) buf[i] = nxt[i];
    }

#pragma unroll
    for (int j = 0; j < 2; ++j) {
        float2* st = states + (size_t)((c * B_SZ + b) * H_SZ + h0 + j) * NM;
#pragma unroll
        for (int n = 0; n < NM; ++n) st[n] = make_float2(sr[j][n], si[j][n]);
    }
}

__global__ void __launch_bounds__(256, 4)
k2_carry_scan(const float* __restrict__ log_dt,
              const float* __restrict__ Arl,
              const float* __restrict__ Aimp,
              float2* __restrict__ states) {
    int g = blockIdx.x * blockDim.x + threadIdx.x;   // [B_SZ * H_SZ * NM)
    int n = g % NM;
    int h = (g / NM) % H_SZ;
    int b = g / (NM * H_SZ);

    float dt  = __expf(log_dt[h]);
    float Are = -__expf(Arl[h * NM + n]);
    float Aim = Aimp[h * NM + n];
    // w^LC = exp(dt*A*LC)
    float er  = __expf(Are * dt * (float)LC);
    float ang = Aim * dt * (float)LC;
    float wr = er * __cosf(ang), wi = er * __sinf(ang);

    // stride between consecutive chunks for this (b,h,n)
    const size_t stride = (size_t)BH * NM;
    float2* base = states + (size_t)(b * H_SZ + h) * NM + n;

    float cr = 0.f, ci = 0.f;
    float2 buf[8], nxt[8];
#pragma unroll
    for (int i = 0; i < 8; ++i) buf[i] = base[(size_t)i * stride];

#pragma unroll
    for (int cb = 0; cb < C_CH / 8; ++cb) {
        if (cb + 1 < C_CH / 8) {
#pragma unroll
            for (int i = 0; i < 8; ++i)
                nxt[i] = base[(size_t)((cb + 1) * 8 + i) * stride];
        }
#pragma unroll
        for (int i = 0; i < 8; ++i) {
            int c = cb * 8 + i;
            base[(size_t)c * stride] = make_float2(cr, ci);  // exclusive carry
            float ncr = fmaf(wr, cr, fmaf(-wi, ci, buf[i].x));
            float nci = fmaf(wr, ci, fmaf(wi, cr, buf[i].y));
            cr = ncr; ci = nci;
        }
#pragma unroll
        for (int i = 0; i < 8; ++i) buf[i] = nxt[i];
    }
}

__global__ void __launch_bounds__(256, 3)
k3_output(const float* __restrict__ x,
          const float* __restrict__ Dp,
          const float* __restrict__ log_dt,
          const float* __restrict__ Arl,
          const float* __restrict__ Aimp,
          const float* __restrict__ Crep,
          const float* __restrict__ Cimp,
          const float2* __restrict__ states,
          float* __restrict__ out) {
    int g = blockIdx.x * blockDim.x + threadIdx.x;   // [C_CH * B_SZ * H2)
    int hp = g % H2;
    int b  = (g / H2) % B_SZ;
    int c  = g / (H2 * B_SZ);
    int h0 = hp * 2;

    float wr[2][NM], wi[2][NM], Are[2][NM], Aim[2][NM];
    load_w2(log_dt, Arl, Aimp, h0, wr, wi, Are, Aim);

    // Cd = (Cre + i*Cim) * (w - 1) / A   (divide via conj(A)/|A|^2)
    float cdr[2][NM], cdi[2][NM];
#pragma unroll
    for (int j = 0; j < 2; ++j) {
        int h = h0 + j;
#pragma unroll
        for (int n = 0; n < NM; ++n) {
            float den = Are[j][n] * Are[j][n] + Aim[j][n] * Aim[j][n];
            float inv = 1.0f / den;
            float tr = ((wr[j][n] - 1.f) * Are[j][n] + wi[j][n] * Aim[j][n]) * inv;
            float ti = (wi[j][n] * Are[j][n] - (wr[j][n] - 1.f) * Aim[j][n]) * inv;
            float Cre = Crep[h * NM + n], Cim = Cimp[h * NM + n];
            cdr[j][n] = Cre * tr - Cim * ti;
            cdi[j][n] = Cre * ti + Cim * tr;
        }
    }

    float sr[2][NM], si[2][NM];
#pragma unroll
    for (int j = 0; j < 2; ++j) {
        const float2* st = states + (size_t)((c * B_SZ + b) * H_SZ + h0 + j) * NM;
#pragma unroll
        for (int n = 0; n < NM; ++n) { float2 v = st[n]; sr[j][n] = v.x; si[j][n] = v.y; }
    }

    float Dv[2] = {Dp[h0], Dp[h0 + 1]};
    const float* xp = x + (size_t)(c * LC) * BH + b * H_SZ + h0;
    float* op = out + (size_t)(c * LC) * BH + b * H_SZ + h0;

    float2 buf[8], nxt[8];
#pragma unroll
    for (int i = 0; i < 8; ++i)
        buf[i] = *(const float2*)(xp + (size_t)i * BH);

#pragma unroll
    for (int tb = 0; tb < LC / 8; ++tb) {
        if (tb + 1 < LC / 8) {
#pragma unroll
            for (int i = 0; i < 8; ++i)
                nxt[i] = *(const float2*)(xp + (size_t)((tb + 1) * 8 + i) * BH);
        }
#pragma unroll
        for (int i = 0; i < 8; ++i) {
            float xv[2] = {buf[i].x, buf[i].y};
            float2 o;
            float y[2];
#pragma unroll
            for (int j = 0; j < 2; ++j) {
                y[j] = 0.f;
#pragma unroll
                for (int n = 0; n < NM; ++n) {
                    float nsr = fmaf(wr[j][n], sr[j][n], fmaf(-wi[j][n], si[j][n], xv[j]));
                    float nsi = fmaf(wr[j][n], si[j][n], wi[j][n] * sr[j][n]);
                    sr[j][n] = nsr; si[j][n] = nsi;
                    y[j] = fmaf(cdr[j][n], nsr, y[j]);
                    y[j] = fmaf(-cdi[j][n], nsi, y[j]);
                }
            }
            o.x = fmaf(Dv[0], xv[0], 2.0f * y[0]);
            o.y = fmaf(Dv[1], xv[1], 2.0f * y[1]);
            *(float2*)(op + (size_t)(tb * 8 + i) * BH) = o;
        }
#pragma unroll
        for (int i = 0; i < 8; ++i) buf[i] = nxt[i];
    }
}

extern "C" void kernel_launch(void* const* d_in, const int* in_sizes, int n_in,
                              void* d_out, int out_size, void* d_ws, size_t ws_size,
                              hipStream_t stream) {
    const float* x      = (const float*)d_in[0];
    const float* Dp     = (const float*)d_in[1];
    const float* log_dt = (const float*)d_in[2];
    const float* Arl    = (const float*)d_in[3];
    const float* Aimp   = (const float*)d_in[4];
    const float* Cre    = (const float*)d_in[5];
    const float* Cim    = (const float*)d_in[6];
    float* out = (float*)d_out;
    float2* states = (float2*)d_ws;   // C_CH*BH*NM float2 = 16.8 MB (fits: round-1 passed)

    int total1 = C_CH * B_SZ * H2;            // 131072 threads
    k1_chunk_end<<<total1 / 256, 256, 0, stream>>>(x, log_dt, Arl, Aimp, states);

    int total2 = B_SZ * H_SZ * NM;            // 32768 threads
    k2_carry_scan<<<total2 / 256, 256, 0, stream>>>(log_dt, Arl, Aimp, states);

    k3_output<<<total1 / 256, 256, 0, stream>>>(x, Dp, log_dt, Arl, Aimp, Cre, Cim,
                                                states, out);
}

// Round 3
// 200.129 us; speedup vs baseline: 1.1050x; 1.1050x over previous
//
#include <hip/hip_runtime.h>

// Problem constants (fixed by the reference).
#define T_LEN 4096
#define B_SZ  2
#define H_SZ  2048
#define NM    8            // N2 complex modes
#define BH    (B_SZ * H_SZ)

// ---------------------------------------------------------------------------
// S4D via chunked linear recurrence (exact equivalent of the FFT conv):
//   S_n(t) = w_n * S_n(t-1) + x(t),  w_n = exp(dt*A_n)
//   out(t) = 2*Re( sum_n Cd_n * S_n(t) ) + D*x(t),  Cd = C*(w-1)/A
// k1: per-(chunk,b,h) local scan -> end states into d_ws
// k2: per-(b,h,n) exclusive scan across chunks -> carry-in per chunk
// k3: per-(chunk,b,h) re-scan from carry-in -> output
//
// Round-2 post-mortem: 2-h-per-thread + batch-8 float2 prefetch demanded
// ~96+ VGPRs -> scratch spills (WRITE_SIZE 16->146 MB). Round 3: 1 h per
// thread, batch-4 prefetch, ~55 VGPRs, launch_bounds(256,8) -> 32 waves/CU
// spill-free; C=128 chunks (ws permitting) to lift grid-limited occupancy.
// ---------------------------------------------------------------------------

__device__ __forceinline__ void load_w1(const float* __restrict__ log_dt,
                                        const float* __restrict__ Arl,
                                        const float* __restrict__ Aimp,
                                        int h, float* wr, float* wi) {
    float dt = __expf(log_dt[h]);
#pragma unroll
    for (int n = 0; n < NM; ++n) {
        float ar  = -__expf(Arl[h * NM + n]);
        float ai  = Aimp[h * NM + n];
        float er  = __expf(ar * dt);
        float ang = ai * dt;
        wr[n] = er * __cosf(ang);
        wi[n] = er * __sinf(ang);
    }
}

template <int LC>
__global__ void __launch_bounds__(256, 8)
k1_chunk_end(const float* __restrict__ x,
             const float* __restrict__ log_dt,
             const float* __restrict__ Arl,
             const float* __restrict__ Aimp,
             float2* __restrict__ states) {
    int g = blockIdx.x * blockDim.x + threadIdx.x;   // [C * BH)
    int h = g % H_SZ;
    int b = (g / H_SZ) % B_SZ;
    int c = g / BH;

    float wr[NM], wi[NM];
    load_w1(log_dt, Arl, Aimp, h, wr, wi);

    float sr[NM], si[NM];
#pragma unroll
    for (int n = 0; n < NM; ++n) { sr[n] = 0.f; si[n] = 0.f; }

    const float* xp = x + (size_t)c * LC * BH + b * H_SZ + h;

    float buf[4], nxt[4];
#pragma unroll
    for (int i = 0; i < 4; ++i) buf[i] = xp[(size_t)i * BH];

#pragma unroll
    for (int tb = 0; tb < LC / 4; ++tb) {
        if (tb + 1 < LC / 4) {
#pragma unroll
            for (int i = 0; i < 4; ++i)
                nxt[i] = xp[(size_t)((tb + 1) * 4 + i) * BH];
        }
#pragma unroll
        for (int i = 0; i < 4; ++i) {
            float xv = buf[i];
#pragma unroll
            for (int n = 0; n < NM; ++n) {
                float nsr = fmaf(wr[n], sr[n], fmaf(-wi[n], si[n], xv));
                float nsi = fmaf(wr[n], si[n], wi[n] * sr[n]);
                sr[n] = nsr; si[n] = nsi;
            }
        }
#pragma unroll
        for (int i = 0; i < 4; ++i) buf[i] = nxt[i];
    }

    float2* st = states + ((size_t)(c * B_SZ + b) * H_SZ + h) * NM;
#pragma unroll
    for (int n = 0; n < NM; ++n) st[n] = make_float2(sr[n], si[n]);
}

template <int CC, int LC>
__global__ void __launch_bounds__(256, 8)
k2_carry_scan(const float* __restrict__ log_dt,
              const float* __restrict__ Arl,
              const float* __restrict__ Aimp,
              float2* __restrict__ states) {
    int g = blockIdx.x * blockDim.x + threadIdx.x;   // [BH * NM)
    int n = g % NM;
    int h = (g / NM) % H_SZ;
    int b = g / (NM * H_SZ);

    float dt  = __expf(log_dt[h]);
    float Are = -__expf(Arl[h * NM + n]);
    float Aim = Aimp[h * NM + n];
    // w^LC = exp(dt*A*LC)
    float er  = __expf(Are * dt * (float)LC);
    float ang = Aim * dt * (float)LC;
    float wr = er * __cosf(ang), wi = er * __sinf(ang);

    const size_t stride = (size_t)BH * NM;           // chunk-to-chunk
    float2* base = states + (size_t)(b * H_SZ + h) * NM + n;

    float cr = 0.f, ci = 0.f;
    float2 buf[4], nxt[4];
#pragma unroll
    for (int i = 0; i < 4; ++i) buf[i] = base[(size_t)i * stride];

#pragma unroll
    for (int cb = 0; cb < CC / 4; ++cb) {
        if (cb + 1 < CC / 4) {
#pragma unroll
            for (int i = 0; i < 4; ++i)
                nxt[i] = base[(size_t)((cb + 1) * 4 + i) * stride];
        }
#pragma unroll
        for (int i = 0; i < 4; ++i) {
            int c = cb * 4 + i;
            base[(size_t)c * stride] = make_float2(cr, ci);  // exclusive carry
            float ncr = fmaf(wr, cr, fmaf(-wi, ci, buf[i].x));
            float nci = fmaf(wr, ci, fmaf(wi, cr, buf[i].y));
            cr = ncr; ci = nci;
        }
#pragma unroll
        for (int i = 0; i < 4; ++i) buf[i] = nxt[i];
    }
}

template <int LC>
__global__ void __launch_bounds__(256, 6)
k3_output(const float* __restrict__ x,
          const float* __restrict__ Dp,
          const float* __restrict__ log_dt,
          const float* __restrict__ Arl,
          const float* __restrict__ Aimp,
          const float* __restrict__ Crep,
          const float* __restrict__ Cimp,
          const float2* __restrict__ states,
          float* __restrict__ out) {
    int g = blockIdx.x * blockDim.x + threadIdx.x;   // [C * BH)
    int h = g % H_SZ;
    int b = (g / H_SZ) % B_SZ;
    int c = g / BH;

    float dt = __expf(log_dt[h]);
    float wr[NM], wi[NM], cdr[NM], cdi[NM];
#pragma unroll
    for (int n = 0; n < NM; ++n) {
        float ar  = -__expf(Arl[h * NM + n]);
        float ai  = Aimp[h * NM + n];
        float er  = __expf(ar * dt);
        float ang = ai * dt;
        float wrn = er * __cosf(ang);
        float win = er * __sinf(ang);
        wr[n] = wrn; wi[n] = win;
        // Cd = (Cre + i*Cim) * (w - 1) / A  (divide via conj(A)/|A|^2)
        float inv = 1.0f / (ar * ar + ai * ai);
        float tr = ((wrn - 1.f) * ar + win * ai) * inv;
        float ti = (win * ar - (wrn - 1.f) * ai) * inv;
        float Cre = Crep[h * NM + n], Cim = Cimp[h * NM + n];
        cdr[n] = Cre * tr - Cim * ti;
        cdi[n] = Cre * ti + Cim * tr;
    }

    const float2* st = states + ((size_t)(c * B_SZ + b) * H_SZ + h) * NM;
    float sr[NM], si[NM];
#pragma unroll
    for (int n = 0; n < NM; ++n) { float2 v = st[n]; sr[n] = v.x; si[n] = v.y; }

    float Dv = Dp[h];
    const float* xp = x + (size_t)c * LC * BH + b * H_SZ + h;
    float* op = out + (size_t)c * LC * BH + b * H_SZ + h;

    float buf[4], nxt[4];
#pragma unroll
    for (int i = 0; i < 4; ++i) buf[i] = xp[(size_t)i * BH];

#pragma unroll
    for (int tb = 0; tb < LC / 4; ++tb) {
        if (tb + 1 < LC / 4) {
#pragma unroll
            for (int i = 0; i < 4; ++i)
                nxt[i] = xp[(size_t)((tb + 1) * 4 + i) * BH];
        }
#pragma unroll
        for (int i = 0; i < 4; ++i) {
            float xv = buf[i];
            float y = 0.f;
#pragma unroll
            for (int n = 0; n < NM; ++n) {
                float nsr = fmaf(wr[n], sr[n], fmaf(-wi[n], si[n], xv));
                float nsi = fmaf(wr[n], si[n], wi[n] * sr[n]);
                sr[n] = nsr; si[n] = nsi;
                y = fmaf(cdr[n], nsr, y);
                y = fmaf(-cdi[n], nsi, y);
            }
            op[(size_t)(tb * 4 + i) * BH] = fmaf(Dv, xv, 2.0f * y);
        }
#pragma unroll
        for (int i = 0; i < 4; ++i) buf[i] = nxt[i];
    }
}

extern "C" void kernel_launch(void* const* d_in, const int* in_sizes, int n_in,
                              void* d_out, int out_size, void* d_ws, size_t ws_size,
                              hipStream_t stream) {
    const float* x      = (const float*)d_in[0];
    const float* Dp     = (const float*)d_in[1];
    const float* log_dt = (const float*)d_in[2];
    const float* Arl    = (const float*)d_in[3];
    const float* Aimp   = (const float*)d_in[4];
    const float* Cre    = (const float*)d_in[5];
    const float* Cim    = (const float*)d_in[6];
    float* out = (float*)d_out;
    float2* states = (float2*)d_ws;

    const size_t need128 = (size_t)128 * BH * NM * sizeof(float2);  // 33.5 MB

    if (ws_size >= need128) {
        constexpr int C = 128, LC = T_LEN / 128;    // LC = 32
        int total1 = C * BH;                        // 524288 threads
        k1_chunk_end<LC><<<total1 / 256, 256, 0, stream>>>(x, log_dt, Arl, Aimp, states);
        int total2 = BH * NM;                       // 32768 threads
        k2_carry_scan<C, LC><<<total2 / 256, 256, 0, stream>>>(log_dt, Arl, Aimp, states);
        k3_output<LC><<<total1 / 256, 256, 0, stream>>>(x, Dp, log_dt, Arl, Aimp,
                                                        Cre, Cim, states, out);
    } else {
        constexpr int C = 64, LC = T_LEN / 64;      // LC = 64 (16.8 MB states)
        int total1 = C * BH;                        // 262144 threads
        k1_chunk_end<LC><<<total1 / 256, 256, 0, stream>>>(x, log_dt, Arl, Aimp, states);
        int total2 = BH * NM;
        k2_carry_scan<C, LC><<<total2 / 256, 256, 0, stream>>>(log_dt, Arl, Aimp, states);
        k3_output<LC><<<total1 / 256, 256, 0, stream>>>(x, Dp, log_dt, Arl, Aimp,
                                                        Cre, Cim, states, out);
    }
}

// Round 4
// 168.532 us; speedup vs baseline: 1.3122x; 1.1875x over previous
//
#include <hip/hip_runtime.h>

// Problem constants (fixed by the reference).
#define T_LEN 4096
#define B_SZ  2
#define H_SZ  2048
#define NM    8            // N2 complex modes
#define BH    (B_SZ * H_SZ)

// ---------------------------------------------------------------------------
// S4D via chunked linear recurrence (exact equivalent of the FFT conv):
//   S_n(t) = w_n * S_n(t-1) + x(t),  w_n = exp(dt*A_n)
//   out(t) = 2*Re( sum_n Cd_n * S_n(t) ) + D*x(t),  Cd = C*(w-1)/A
//
// states layout: [c][b][n][h] float2 — lanes are consecutive h, so every
// states access is one dense 512 B wave transaction (round-3 layout [h][n]
// gave 8 partial-line stores; k1 WRITE_SIZE was 90 MB vs 33.5 ideal).
// launch_bounds(256,4): 128-VGPR cap — round-3's (256,8)/64-cap spilled.
// ---------------------------------------------------------------------------

template <int LC>
__global__ void __launch_bounds__(256, 4)
k1_chunk_end(const float* __restrict__ x,
             const float* __restrict__ log_dt,
             const float* __restrict__ Arl,
             const float* __restrict__ Aimp,
             float2* __restrict__ states) {
    int g = blockIdx.x * blockDim.x + threadIdx.x;   // [C * BH)
    int h = g % H_SZ;
    int b = (g / H_SZ) % B_SZ;
    int c = g / BH;

    float dt = __expf(log_dt[h]);
    float wr[NM], wi[NM];
#pragma unroll
    for (int n = 0; n < NM; ++n) {
        float ar  = -__expf(Arl[h * NM + n]);
        float ai  = Aimp[h * NM + n];
        float er  = __expf(ar * dt);
        float ang = ai * dt;
        wr[n] = er * __cosf(ang);
        wi[n] = er * __sinf(ang);
    }

    float sr[NM], si[NM];
#pragma unroll
    for (int n = 0; n < NM; ++n) { sr[n] = 0.f; si[n] = 0.f; }

    const float* xp = x + (size_t)c * LC * BH + b * H_SZ + h;

    constexpr int BT = 8;
    float buf[BT], nxt[BT];
#pragma unroll
    for (int i = 0; i < BT; ++i) buf[i] = xp[(size_t)i * BH];

#pragma unroll
    for (int tb = 0; tb < LC / BT; ++tb) {
        if (tb + 1 < LC / BT) {
#pragma unroll
            for (int i = 0; i < BT; ++i)
                nxt[i] = xp[(size_t)((tb + 1) * BT + i) * BH];
        }
#pragma unroll
        for (int i = 0; i < BT; ++i) {
            float xv = buf[i];
#pragma unroll
            for (int n = 0; n < NM; ++n) {
                float nsr = fmaf(wr[n], sr[n], fmaf(-wi[n], si[n], xv));
                float nsi = fmaf(wr[n], si[n], wi[n] * sr[n]);
                sr[n] = nsr; si[n] = nsi;
            }
        }
#pragma unroll
        for (int i = 0; i < BT; ++i) buf[i] = nxt[i];
    }

    // states[c][b][n][h]
    float2* st = states + (size_t)(c * B_SZ + b) * NM * H_SZ + h;
#pragma unroll
    for (int n = 0; n < NM; ++n) st[(size_t)n * H_SZ] = make_float2(sr[n], si[n]);
}

template <int CC, int LC>
__global__ void __launch_bounds__(256, 4)
k2_carry_scan(const float* __restrict__ log_dt,
              const float* __restrict__ Arl,
              const float* __restrict__ Aimp,
              float2* __restrict__ states) {
    int g = blockIdx.x * blockDim.x + threadIdx.x;   // [BH * NM), h fastest
    int h = g % H_SZ;
    int n = (g / H_SZ) % NM;
    int b = g / (H_SZ * NM);

    float dt  = __expf(log_dt[h]);
    float Are = -__expf(Arl[h * NM + n]);
    float Aim = Aimp[h * NM + n];
    // w^LC = exp(dt*A*LC)
    float er  = __expf(Are * dt * (float)LC);
    float ang = Aim * dt * (float)LC;
    float wr = er * __cosf(ang), wi = er * __sinf(ang);

    const size_t stride = (size_t)B_SZ * NM * H_SZ;  // chunk-to-chunk
    float2* base = states + ((size_t)b * NM + n) * H_SZ + h;

    float cr = 0.f, ci = 0.f;
    constexpr int BT = 8;
    float2 buf[BT], nxt[BT];
#pragma unroll
    for (int i = 0; i < BT; ++i) buf[i] = base[(size_t)i * stride];

#pragma unroll
    for (int cb = 0; cb < CC / BT; ++cb) {
        if (cb + 1 < CC / BT) {
#pragma unroll
            for (int i = 0; i < BT; ++i)
                nxt[i] = base[(size_t)((cb + 1) * BT + i) * stride];
        }
#pragma unroll
        for (int i = 0; i < BT; ++i) {
            int c = cb * BT + i;
            base[(size_t)c * stride] = make_float2(cr, ci);  // exclusive carry
            float ncr = fmaf(wr, cr, fmaf(-wi, ci, buf[i].x));
            float nci = fmaf(wr, ci, fmaf(wi, cr, buf[i].y));
            cr = ncr; ci = nci;
        }
#pragma unroll
        for (int i = 0; i < BT; ++i) buf[i] = nxt[i];
    }
}

template <int LC>
__global__ void __launch_bounds__(256, 4)
k3_output(const float* __restrict__ x,
          const float* __restrict__ Dp,
          const float* __restrict__ log_dt,
          const float* __restrict__ Arl,
          const float* __restrict__ Aimp,
          const float* __restrict__ Crep,
          const float* __restrict__ Cimp,
          const float2* __restrict__ states,
          float* __restrict__ out) {
    int g = blockIdx.x * blockDim.x + threadIdx.x;   // [C * BH)
    int h = g % H_SZ;
    int b = (g / H_SZ) % B_SZ;
    int c = g / BH;

    float dt = __expf(log_dt[h]);
    float wr[NM], wi[NM], cdr[NM], cdi[NM];
#pragma unroll
    for (int n = 0; n < NM; ++n) {
        float ar  = -__expf(Arl[h * NM + n]);
        float ai  = Aimp[h * NM + n];
        float er  = __expf(ar * dt);
        float ang = ai * dt;
        float wrn = er * __cosf(ang);
        float win = er * __sinf(ang);
        wr[n] = wrn; wi[n] = win;
        // Cd = (Cre + i*Cim) * (w - 1) / A  (divide via conj(A)/|A|^2)
        float inv = 1.0f / (ar * ar + ai * ai);
        float tr = ((wrn - 1.f) * ar + win * ai) * inv;
        float ti = (win * ar - (wrn - 1.f) * ai) * inv;
        float Cre = Crep[h * NM + n], Cim = Cimp[h * NM + n];
        cdr[n] = Cre * tr - Cim * ti;
        cdi[n] = Cre * ti + Cim * tr;
    }

    // carry-in: states[c][b][n][h]
    const float2* st = states + (size_t)(c * B_SZ + b) * NM * H_SZ + h;
    float sr[NM], si[NM];
#pragma unroll
    for (int n = 0; n < NM; ++n) {
        float2 v = st[(size_t)n * H_SZ];
        sr[n] = v.x; si[n] = v.y;
    }

    float Dv = Dp[h];
    const float* xp = x + (size_t)c * LC * BH + b * H_SZ + h;
    float* op = out + (size_t)c * LC * BH + b * H_SZ + h;

    constexpr int BT = 8;
    float buf[BT], nxt[BT];
#pragma unroll
    for (int i = 0; i < BT; ++i) buf[i] = xp[(size_t)i * BH];

#pragma unroll
    for (int tb = 0; tb < LC / BT; ++tb) {
        if (tb + 1 < LC / BT) {
#pragma unroll
            for (int i = 0; i < BT; ++i)
                nxt[i] = xp[(size_t)((tb + 1) * BT + i) * BH];
        }
#pragma unroll
        for (int i = 0; i < BT; ++i) {
            float xv = buf[i];
            float y = 0.f;
#pragma unroll
            for (int n = 0; n < NM; ++n) {
                float nsr = fmaf(wr[n], sr[n], fmaf(-wi[n], si[n], xv));
                float nsi = fmaf(wr[n], si[n], wi[n] * sr[n]);
                sr[n] = nsr; si[n] = nsi;
                y = fmaf(cdr[n], nsr, y);
                y = fmaf(-cdi[n], nsi, y);
            }
            float ov = fmaf(Dv, xv, 2.0f * y);
            __builtin_nontemporal_store(ov, op + (size_t)(tb * BT + i) * BH);
        }
#pragma unroll
        for (int i = 0; i < BT; ++i) buf[i] = nxt[i];
    }
}

extern "C" void kernel_launch(void* const* d_in, const int* in_sizes, int n_in,
                              void* d_out, int out_size, void* d_ws, size_t ws_size,
                              hipStream_t stream) {
    const float* x      = (const float*)d_in[0];
    const float* Dp     = (const float*)d_in[1];
    const float* log_dt = (const float*)d_in[2];
    const float* Arl    = (const float*)d_in[3];
    const float* Aimp   = (const float*)d_in[4];
    const float* Cre    = (const float*)d_in[5];
    const float* Cim    = (const float*)d_in[6];
    float* out = (float*)d_out;
    float2* states = (float2*)d_ws;

    const size_t need128 = (size_t)128 * BH * NM * sizeof(float2);  // 33.5 MB

    if (ws_size >= need128) {
        constexpr int C = 128, LC = T_LEN / 128;    // LC = 32
        int total1 = C * BH;                        // 524288 threads
        k1_chunk_end<LC><<<total1 / 256, 256, 0, stream>>>(x, log_dt, Arl, Aimp, states);
        int total2 = BH * NM;                       // 32768 threads
        k2_carry_scan<C, LC><<<total2 / 256, 256, 0, stream>>>(log_dt, Arl, Aimp, states);
        k3_output<LC><<<total1 / 256, 256, 0, stream>>>(x, Dp, log_dt, Arl, Aimp,
                                                        Cre, Cim, states, out);
    } else {
        constexpr int C = 64, LC = T_LEN / 64;      // LC = 64 (16.8 MB states)
        int total1 = C * BH;
        k1_chunk_end<LC><<<total1 / 256, 256, 0, stream>>>(x, log_dt, Arl, Aimp, states);
        int total2 = BH * NM;
        k2_carry_scan<C, LC><<<total2 / 256, 256, 0, stream>>>(log_dt, Arl, Aimp, states);
        k3_output<LC><<<total1 / 256, 256, 0, stream>>>(x, Dp, log_dt, Arl, Aimp,
                                                        Cre, Cim, states, out);
    }
}

// Round 5
// 151.660 us; speedup vs baseline: 1.4581x; 1.1112x over previous
//
#include <hip/hip_runtime.h>

// Problem constants (fixed by the reference).
#define T_LEN 4096
#define B_SZ  2
#define H_SZ  2048
#define NM    8            // N2 complex modes
#define BH    (B_SZ * H_SZ)

// ---------------------------------------------------------------------------
// S4D via chunked linear recurrence (exact equivalent of the FFT conv):
//   S_n(t) = w_n * S_n(t-1) + x(t),  w_n = exp(dt*A_n)
//   out(t) = 2*Re( sum_n Cd_n * S_n(t) ) + D*x(t),  Cd = C*(w-1)/A
//
// Round-4 post-mortem: all three kernels dropped below the harness's 41 µs
// ws-poison fills (which sit inside the measured window; ~75 µs of the
// dur_us is harness reset). Round 5: C=64 chunks — halves the states
// round-trip (134->67 MB) while keeping 16 waves/CU in k1/k3.
// states layout [c][b][n][h]: every states access is one dense 512 B
// wave transaction. launch_bounds(256,4) = 128-VGPR cap (spill-free since r4).
// ---------------------------------------------------------------------------

template <int LC>
__global__ void __launch_bounds__(256, 4)
k1_chunk_end(const float* __restrict__ x,
             const float* __restrict__ log_dt,
             const float* __restrict__ Arl,
             const float* __restrict__ Aimp,
             float2* __restrict__ states) {
    int g = blockIdx.x * blockDim.x + threadIdx.x;   // [C * BH)
    int h = g % H_SZ;
    int b = (g / H_SZ) % B_SZ;
    int c = g / BH;

    float dt = __expf(log_dt[h]);
    float wr[NM], wi[NM];
#pragma unroll
    for (int n = 0; n < NM; ++n) {
        float ar  = -__expf(Arl[h * NM + n]);
        float ai  = Aimp[h * NM + n];
        float er  = __expf(ar * dt);
        float ang = ai * dt;
        wr[n] = er * __cosf(ang);
        wi[n] = er * __sinf(ang);
    }

    float sr[NM], si[NM];
#pragma unroll
    for (int n = 0; n < NM; ++n) { sr[n] = 0.f; si[n] = 0.f; }

    const float* xp = x + (size_t)c * LC * BH + b * H_SZ + h;

    constexpr int BT = 8;
    float buf[BT], nxt[BT];
#pragma unroll
    for (int i = 0; i < BT; ++i) buf[i] = xp[(size_t)i * BH];

#pragma unroll
    for (int tb = 0; tb < LC / BT; ++tb) {
        if (tb + 1 < LC / BT) {
#pragma unroll
            for (int i = 0; i < BT; ++i)
                nxt[i] = xp[(size_t)((tb + 1) * BT + i) * BH];
        }
#pragma unroll
        for (int i = 0; i < BT; ++i) {
            float xv = buf[i];
#pragma unroll
            for (int n = 0; n < NM; ++n) {
                float nsr = fmaf(wr[n], sr[n], fmaf(-wi[n], si[n], xv));
                float nsi = fmaf(wr[n], si[n], wi[n] * sr[n]);
                sr[n] = nsr; si[n] = nsi;
            }
        }
#pragma unroll
        for (int i = 0; i < BT; ++i) buf[i] = nxt[i];
    }

    // states[c][b][n][h]
    float2* st = states + (size_t)(c * B_SZ + b) * NM * H_SZ + h;
#pragma unroll
    for (int n = 0; n < NM; ++n) st[(size_t)n * H_SZ] = make_float2(sr[n], si[n]);
}

template <int CC, int LC>
__global__ void __launch_bounds__(256, 4)
k2_carry_scan(const float* __restrict__ log_dt,
              const float* __restrict__ Arl,
              const float* __restrict__ Aimp,
              float2* __restrict__ states) {
    int g = blockIdx.x * blockDim.x + threadIdx.x;   // [BH * NM), h fastest
    int h = g % H_SZ;
    int n = (g / H_SZ) % NM;
    int b = g / (H_SZ * NM);

    float dt  = __expf(log_dt[h]);
    float Are = -__expf(Arl[h * NM + n]);
    float Aim = Aimp[h * NM + n];
    // w^LC = exp(dt*A*LC)
    float er  = __expf(Are * dt * (float)LC);
    float ang = Aim * dt * (float)LC;
    float wr = er * __cosf(ang), wi = er * __sinf(ang);

    const size_t stride = (size_t)B_SZ * NM * H_SZ;  // chunk-to-chunk
    float2* base = states + ((size_t)b * NM + n) * H_SZ + h;

    float cr = 0.f, ci = 0.f;
    constexpr int BT = 8;
    float2 buf[BT], nxt[BT];
#pragma unroll
    for (int i = 0; i < BT; ++i) buf[i] = base[(size_t)i * stride];

#pragma unroll
    for (int cb = 0; cb < CC / BT; ++cb) {
        if (cb + 1 < CC / BT) {
#pragma unroll
            for (int i = 0; i < BT; ++i)
                nxt[i] = base[(size_t)((cb + 1) * BT + i) * stride];
        }
#pragma unroll
        for (int i = 0; i < BT; ++i) {
            int c = cb * BT + i;
            base[(size_t)c * stride] = make_float2(cr, ci);  // exclusive carry
            float ncr = fmaf(wr, cr, fmaf(-wi, ci, buf[i].x));
            float nci = fmaf(wr, ci, fmaf(wi, cr, buf[i].y));
            cr = ncr; ci = nci;
        }
#pragma unroll
        for (int i = 0; i < BT; ++i) buf[i] = nxt[i];
    }
}

template <int LC>
__global__ void __launch_bounds__(256, 4)
k3_output(const float* __restrict__ x,
          const float* __restrict__ Dp,
          const float* __restrict__ log_dt,
          const float* __restrict__ Arl,
          const float* __restrict__ Aimp,
          const float* __restrict__ Crep,
          const float* __restrict__ Cimp,
          const float2* __restrict__ states,
          float* __restrict__ out) {
    int g = blockIdx.x * blockDim.x + threadIdx.x;   // [C * BH)
    int h = g % H_SZ;
    int b = (g / H_SZ) % B_SZ;
    int c = g / BH;

    float dt = __expf(log_dt[h]);
    float wr[NM], wi[NM], cdr[NM], cdi[NM];
#pragma unroll
    for (int n = 0; n < NM; ++n) {
        float ar  = -__expf(Arl[h * NM + n]);
        float ai  = Aimp[h * NM + n];
        float er  = __expf(ar * dt);
        float ang = ai * dt;
        float wrn = er * __cosf(ang);
        float win = er * __sinf(ang);
        wr[n] = wrn; wi[n] = win;
        // Cd = (Cre + i*Cim) * (w - 1) / A  (divide via conj(A)/|A|^2)
        float inv = 1.0f / (ar * ar + ai * ai);
        float tr = ((wrn - 1.f) * ar + win * ai) * inv;
        float ti = (win * ar - (wrn - 1.f) * ai) * inv;
        float Cre = Crep[h * NM + n], Cim = Cimp[h * NM + n];
        cdr[n] = Cre * tr - Cim * ti;
        cdi[n] = Cre * ti + Cim * tr;
    }

    // carry-in: states[c][b][n][h]
    const float2* st = states + (size_t)(c * B_SZ + b) * NM * H_SZ + h;
    float sr[NM], si[NM];
#pragma unroll
    for (int n = 0; n < NM; ++n) {
        float2 v = st[(size_t)n * H_SZ];
        sr[n] = v.x; si[n] = v.y;
    }

    float Dv = Dp[h];
    const float* xp = x + (size_t)c * LC * BH + b * H_SZ + h;
    float* op = out + (size_t)c * LC * BH + b * H_SZ + h;

    constexpr int BT = 8;
    float buf[BT], nxt[BT];
#pragma unroll
    for (int i = 0; i < BT; ++i) buf[i] = xp[(size_t)i * BH];

#pragma unroll
    for (int tb = 0; tb < LC / BT; ++tb) {
        if (tb + 1 < LC / BT) {
#pragma unroll
            for (int i = 0; i < BT; ++i)
                nxt[i] = xp[(size_t)((tb + 1) * BT + i) * BH];
        }
#pragma unroll
        for (int i = 0; i < BT; ++i) {
            float xv = buf[i];
            float y = 0.f;
#pragma unroll
            for (int n = 0; n < NM; ++n) {
                float nsr = fmaf(wr[n], sr[n], fmaf(-wi[n], si[n], xv));
                float nsi = fmaf(wr[n], si[n], wi[n] * sr[n]);
                sr[n] = nsr; si[n] = nsi;
                y = fmaf(cdr[n], nsr, y);
                y = fmaf(-cdi[n], nsi, y);
            }
            float ov = fmaf(Dv, xv, 2.0f * y);
            __builtin_nontemporal_store(ov, op + (size_t)(tb * BT + i) * BH);
        }
#pragma unroll
        for (int i = 0; i < BT; ++i) buf[i] = nxt[i];
    }
}

extern "C" void kernel_launch(void* const* d_in, const int* in_sizes, int n_in,
                              void* d_out, int out_size, void* d_ws, size_t ws_size,
                              hipStream_t stream) {
    const float* x      = (const float*)d_in[0];
    const float* Dp     = (const float*)d_in[1];
    const float* log_dt = (const float*)d_in[2];
    const float* Arl    = (const float*)d_in[3];
    const float* Aimp   = (const float*)d_in[4];
    const float* Cre    = (const float*)d_in[5];
    const float* Cim    = (const float*)d_in[6];
    float* out = (float*)d_out;
    float2* states = (float2*)d_ws;

    const size_t need64 = (size_t)64 * BH * NM * sizeof(float2);   // 16.8 MB

    if (ws_size >= need64) {
        constexpr int C = 64, LC = T_LEN / 64;      // LC = 64
        int total1 = C * BH;                        // 262144 threads
        k1_chunk_end<LC><<<total1 / 256, 256, 0, stream>>>(x, log_dt, Arl, Aimp, states);
        int total2 = BH * NM;                       // 32768 threads
        k2_carry_scan<C, LC><<<total2 / 256, 256, 0, stream>>>(log_dt, Arl, Aimp, states);
        k3_output<LC><<<total1 / 256, 256, 0, stream>>>(x, Dp, log_dt, Arl, Aimp,
                                                        Cre, Cim, states, out);
    } else {
        constexpr int C = 32, LC = T_LEN / 32;      // LC = 128 (8.4 MB states)
        int total1 = C * BH;
        k1_chunk_end<LC><<<total1 / 256, 256, 0, stream>>>(x, log_dt, Arl, Aimp, states);
        int total2 = BH * NM;
        k2_carry_scan<C, LC><<<total2 / 256, 256, 0, stream>>>(log_dt, Arl, Aimp, states);
        k3_output<LC><<<total1 / 256, 256, 0, stream>>>(x, Dp, log_dt, Arl, Aimp,
                                                        Cre, Cim, states, out);
    }
}